// Round 8
// baseline (79.361 us; speedup 1.0000x reference)
//
#include <hip/hip_runtime.h>
#include <math.h>

#define NROWS 8192
#define DIM 512
#define INV_T 20.0f
#define QS 500.0f
// dequant * 1/T * log2(e), for exp2-based softmax accumulation
#define DEQ2 (INV_T * 1.4426950408889634f / (QS * QS))

typedef __attribute__((ext_vector_type(4))) int i32x4;

__device__ __forceinline__ void gload_lds16(const void* g, void* l) {
    __builtin_amdgcn_global_load_lds(
        (const __attribute__((address_space(1))) unsigned int*)g,
        (__attribute__((address_space(3))) unsigned int*)l, 16, 0, 0);
}

__device__ __forceinline__ float hw_exp2(float x) {
    float r;
    asm("v_exp_f32 %0, %1" : "=v"(r) : "v"(x));  // D = 2^S0, 1 inst
    return r;
}

__device__ __forceinline__ float dot4(float4 a, float4 b) {
    return a.x * b.x + a.y * b.y + a.z * b.z + a.w * b.w;
}

__device__ __forceinline__ int q4(float4 v, float s) {
    int b0 = __float2int_rn(fminf(fmaxf(v.x * s, -127.f), 127.f)) & 255;
    int b1 = __float2int_rn(fminf(fmaxf(v.y * s, -127.f), 127.f)) & 255;
    int b2 = __float2int_rn(fminf(fmaxf(v.z * s, -127.f), 127.f)) & 255;
    int b3 = __float2int_rn(fminf(fmaxf(v.w * s, -127.f), 127.f)) & 255;
    return b0 | (b1 << 8) | (b2 << 16) | (b3 << 24);
}

// One wave per row: L2-normalize, quantize to i8 (scale QS), exact fp32 diag,
// column log2-weights (0 or 1), zero row-sum accumulator.
__global__ __launch_bounds__(256) void norm_kernel(
    const float* __restrict__ A, const float* __restrict__ S,
    const int* __restrict__ labels, signed char* __restrict__ aQ,
    signed char* __restrict__ sQ, float* __restrict__ diag,
    float* __restrict__ lw2, float* __restrict__ lsum) {
    const int wave = threadIdx.x >> 6, lane = threadIdx.x & 63;
    const int row = blockIdx.x * 4 + wave;
    const float4* a4 = (const float4*)(A + (size_t)row * DIM);
    const float4* s4 = (const float4*)(S + (size_t)row * DIM);
    float4 a0 = a4[lane], a1 = a4[lane + 64];
    float4 s0 = s4[lane], s1 = s4[lane + 64];
    float saa = dot4(a0, a0) + dot4(a1, a1);
    float sss = dot4(s0, s0) + dot4(s1, s1);
    float sas = dot4(a0, s0) + dot4(a1, s1);
    for (int m = 1; m < 64; m <<= 1) {
        saa += __shfl_xor(saa, m);
        sss += __shfl_xor(sss, m);
        sas += __shfl_xor(sas, m);
    }
    const float ra = rsqrtf(saa), rs = rsqrtf(sss);
    signed char* arow = aQ + (size_t)row * DIM;
    signed char* srow = sQ + (size_t)row * DIM;
    *(int*)(arow + lane * 4)       = q4(a0, ra * QS);
    *(int*)(arow + 256 + lane * 4) = q4(a1, ra * QS);
    *(int*)(srow + lane * 4)       = q4(s0, rs * QS);
    *(int*)(srow + 256 + lane * 4) = q4(s1, rs * QS);
    if (lane == 0) {
        diag[row] = sas * ra * rs * INV_T;
        // Uniform column weighting (incl. diagonal) is exact for the final
        // loss: only label==1 rows' lse is consumed, and those rows' diagonal
        // column has log_w==0 in the reference anyway. log2-weight: 0 or 1.
        lw2[row] = (labels[row] == 0) ? 1.0f : 0.0f;
        lsum[row] = 0.0f;
    }
}

// ---------------------------------------------------------------------------
// Barrier-free fused i8 GEMM + exp2 + row-sum (v8: zero in-loop addr VALU).
// Block = 64 rows x 1024 cols; 4 waves with disjoint 64-col slices.
// A panel stored K-SUBTILED: lds[0..32K) = 8 subtiles of [64 rows][4 slots],
// so every in-loop ds_read is (one base VGPR) + compile-time immediate.
// B: per-wave private 2x4KB dbuf at lds[32K + wave*8K). Zero main-loop
// barriers; per-wave counted vmcnt(4); 4-slot involution swizzle everywhere
// (r3/r4-verified). 64 KB LDS -> 2 blocks/CU, self-timed waves.
// ---------------------------------------------------------------------------
#define BM 64

__global__ __launch_bounds__(256) void lse_gemm(
    const signed char* __restrict__ Aq, const signed char* __restrict__ Bq,
    const float* __restrict__ lw2, float* __restrict__ lsum) {
    __shared__ __align__(16) char lds[65536];

    const int bid = blockIdx.x;                 // 1024 blocks
    const int rt = bid & 127, ctg = bid >> 7;   // rt-consecutive -> XCD spread
    const int row0 = rt * BM;
    const int colg = ctg * 1024;

    const int tid = threadIdx.x;
    const int wave = tid >> 6, lane = tid & 63;
    const int fr = lane & 15, grp = lane >> 4;

    // ---- A panel staging, k-subtiled: round k covers subtile k (4 KB).
    // Thread t -> dest byte k*4096 + t*16 -> row t>>2, phys slot t&3;
    // fetch logical slot (t&3)^((t>>3)&3)  [4-slot involution, verified].
    {
        const int rowA = tid >> 2;
        const int slA = (tid & 3) ^ ((tid >> 3) & 3);
        const signed char* Asrc = Aq + (size_t)(row0 + rowA) * DIM + slA * 16;
#pragma unroll
        for (int k = 0; k < 8; ++k)
            gload_lds16(Asrc + k * 64, lds + k * 4096 + wave * 1024);
    }

    // ---- private B staging (per wave, 4 KB window = 64 rows x 64 B):
    // load i, lane l: dest = win + i*1024 + l*16 -> row i*16+(l>>2), phys
    // slot l&3; fetch logical slot (l&3)^((l>>3)&3).
    const int brow = lane >> 2;
    const int bsl = (lane & 3) ^ ((lane >> 3) & 3);
    const signed char* Bwave =
        Bq + (size_t)(colg + wave * 64 + brow) * DIM + bsl * 16;
    char* bwin = lds + 32768 + wave * 8192;  // this wave's 2x4KB dbuf

    // window (CT,K) src offset: CT*131072 + i*8192 + K*64 (compile-time here)
#define STAGE_B(buf, CT, K)                                                   \
    do {                                                                      \
        _Pragma("unroll")                                                     \
        for (int i = 0; i < 4; ++i)                                           \
            gload_lds16(Bwave + (CT) * 131072 + i * 8192 + (K) * 64,          \
                        bwin + (buf) * 4096 + i * 1024);                      \
    } while (0)

    STAGE_B(0, 0, 0);  // first B window; in flight across the barrier

    asm volatile("s_waitcnt vmcnt(4)" ::: "memory");  // A panel staged
    asm volatile("" ::: "memory");
    __builtin_amdgcn_s_barrier();                     // the ONLY barrier
    asm volatile("" ::: "memory");

    // single per-thread LDS base; all reads are base + immediate
    const int base = fr * 64 + ((grp ^ ((fr >> 1) & 3)) << 4);
    const char* ldsRd = lds + base;

    float rsum[4][4] = {};  // [m][j] accumulated across all 4 ct

#pragma unroll
    for (int ct = 0; ct < 4; ++ct) {
        i32x4 acc[4][4] = {};
#pragma unroll
        for (int k = 0; k < 8; ++k) {
            const int w = ct * 8 + k;
            const int cur = w & 1;
            // WAR guard (free: compiler waits already drained lgkm for MFMA)
            asm volatile("s_waitcnt lgkmcnt(0)" ::: "memory");
            if (w < 31) {
                const int w2 = w + 1;
                STAGE_B(cur ^ 1, w2 >> 3, w2 & 7);
            }

            i32x4 a[4], b[4];
            // A reads: no vmcnt dependency -> issue under the wait
#pragma unroll
            for (int m = 0; m < 4; ++m)
                a[m] = *(const i32x4*)(ldsRd + k * 4096 + m * 1024);
            if (w < 31)
                asm volatile("s_waitcnt vmcnt(4)" ::: "memory");
            else
                asm volatile("s_waitcnt vmcnt(0)" ::: "memory");
#pragma unroll
            for (int n = 0; n < 4; ++n)
                b[n] = *(const i32x4*)(ldsRd + 32768 + wave * 8192 +
                                       cur * 4096 + n * 1024);
            __builtin_amdgcn_s_setprio(1);
#pragma unroll
            for (int m = 0; m < 4; ++m)
#pragma unroll
                for (int n = 0; n < 4; ++n)
                    acc[m][n] = __builtin_amdgcn_mfma_i32_16x16x64_i8(
                        a[m], b[n], acc[m][n], 0, 0, 0);
            __builtin_amdgcn_s_setprio(0);
        }

        // per-ct epilogue: uniform column weights, hw exp2 (1 inst), overlaps
        // the already-issued next-window stage.
        const int col0 = colg + ct * 256 + wave * 64;
        float lwv[4];
#pragma unroll
        for (int n = 0; n < 4; ++n)
            lwv[n] = lw2[col0 + n * 16 + fr];
#pragma unroll
        for (int m = 0; m < 4; ++m)
#pragma unroll
            for (int n = 0; n < 4; ++n)
#pragma unroll
                for (int j = 0; j < 4; ++j)
                    rsum[m][j] += hw_exp2(fmaf((float)acc[m][n][j], DEQ2, lwv[n]));
    }
#undef STAGE_B

    // final: reduce rsum over the 16-lane fr group, one atomicAdd per row
#pragma unroll
    for (int m = 0; m < 4; ++m)
#pragma unroll
        for (int j = 0; j < 4; ++j) {
            float v = rsum[m][j];
            v += __shfl_xor(v, 1);
            v += __shfl_xor(v, 2);
            v += __shfl_xor(v, 4);
            v += __shfl_xor(v, 8);
            if (fr == 0)
                atomicAdd(&lsum[row0 + m * 16 + grp * 4 + j], v);
        }
}

// 1024 threads, single block: final scalar reduction.
__global__ __launch_bounds__(1024) void finalize_kernel(
    const float* __restrict__ lsum, const float* __restrict__ diag,
    const int* __restrict__ labels, float* __restrict__ out) {
    const int tid = threadIdx.x;
    float sl = 0.f, sd = 0.f, mx = -1e9f;
    int np_ = 0, nn_ = 0;
#pragma unroll
    for (int i = tid; i < NROWS; i += 1024) {
        const float dg = diag[i];
        if (labels[i] == 1) {
            sl += logf(lsum[i]) - dg;
            sd += dg;
            np_++;
        } else {
            nn_++;
            mx = fmaxf(mx, dg);
        }
    }
    for (int m = 1; m < 64; m <<= 1) {
        sl += __shfl_xor(sl, m);
        sd += __shfl_xor(sd, m);
        mx = fmaxf(mx, __shfl_xor(mx, m));
        np_ += __shfl_xor(np_, m);
        nn_ += __shfl_xor(nn_, m);
    }
    __shared__ float rsl[16], rsd[16], rmx[16];
    __shared__ int rnp[16], rnn[16];
    const int wave = tid >> 6, lane = tid & 63;
    if (lane == 0) {
        rsl[wave] = sl; rsd[wave] = sd; rmx[wave] = mx;
        rnp[wave] = np_; rnn[wave] = nn_;
    }
    __syncthreads();
    if (tid == 0) {
        float SL = 0.f, SD = 0.f, MX = -1e9f;
        int NP = 0, NN = 0;
        for (int w = 0; w < 16; w++) {
            SL += rsl[w]; SD += rsd[w]; MX = fmaxf(MX, rmx[w]);
            NP += rnp[w]; NN += rnn[w];
        }
        const float infonce = SL / (float)NP;
        const float meanpos = SD / (float)NP;
        float pen = fmaxf(MX - meanpos + 0.2f, 0.0f);
        if (NN == 0) pen = 0.0f;
        out[0] = infonce + pen;
    }
}

extern "C" void kernel_launch(void* const* d_in, const int* in_sizes, int n_in,
                              void* d_out, int out_size, void* d_ws, size_t ws_size,
                              hipStream_t stream) {
    const float* A = (const float*)d_in[0];
    const float* S = (const float*)d_in[1];
    const int* labels = (const int*)d_in[2];
    float* out = (float*)d_out;

    char* ws = (char*)d_ws;
    signed char* aQ = (signed char*)ws;                          // 4 MB
    signed char* sQ = (signed char*)(ws + (size_t)NROWS * DIM);  // 4 MB
    char* p = ws + (size_t)NROWS * DIM * 2;
    float* diag = (float*)p;                // 32 KB
    float* lw2 = (float*)(p + 32768);       // 32 KB
    float* lsum = (float*)(p + 65536);      // 32 KB

    norm_kernel<<<NROWS / 4, 256, 0, stream>>>(A, S, labels, aQ, sQ, diag, lw2, lsum);
    lse_gemm<<<128 * 8, 256, 0, stream>>>(aQ, sQ, lw2, lsum);
    finalize_kernel<<<1, 1024, 0, stream>>>(lsum, diag, labels, out);
}

// Round 9
// 72.440 us; speedup vs baseline: 1.0955x; 1.0955x over previous
//
#include <hip/hip_runtime.h>
#include <math.h>

#define NROWS 8192
#define DIM 512
#define INV_T 20.0f
#define QS 500.0f
// dequant * 1/T * log2(e), for exp2-based softmax accumulation
#define DEQ2 (INV_T * 1.4426950408889634f / (QS * QS))

typedef __attribute__((ext_vector_type(4))) int i32x4;

__device__ __forceinline__ float hw_exp2(float x) {
    float r;
    asm("v_exp_f32 %0, %1" : "=v"(r) : "v"(x));  // D = 2^S0, 1 inst
    return r;
}

__device__ __forceinline__ float dot4(float4 a, float4 b) {
    return a.x * b.x + a.y * b.y + a.z * b.z + a.w * b.w;
}

__device__ __forceinline__ int q4(float4 v, float s) {
    int b0 = __float2int_rn(fminf(fmaxf(v.x * s, -127.f), 127.f)) & 255;
    int b1 = __float2int_rn(fminf(fmaxf(v.y * s, -127.f), 127.f)) & 255;
    int b2 = __float2int_rn(fminf(fmaxf(v.z * s, -127.f), 127.f)) & 255;
    int b3 = __float2int_rn(fminf(fmaxf(v.w * s, -127.f), 127.f)) & 255;
    return b0 | (b1 << 8) | (b2 << 16) | (b3 << 24);
}

// One wave per row: L2-normalize, quantize to i8 (scale QS), exact fp32 diag,
// column log2-weights (0 or 1), zero row-sum accumulator.
__global__ __launch_bounds__(256) void norm_kernel(
    const float* __restrict__ A, const float* __restrict__ S,
    const int* __restrict__ labels, signed char* __restrict__ aQ,
    signed char* __restrict__ sQ, float* __restrict__ diag,
    float* __restrict__ lw2, float* __restrict__ lsum) {
    const int wave = threadIdx.x >> 6, lane = threadIdx.x & 63;
    const int row = blockIdx.x * 4 + wave;
    const float4* a4 = (const float4*)(A + (size_t)row * DIM);
    const float4* s4 = (const float4*)(S + (size_t)row * DIM);
    float4 a0 = a4[lane], a1 = a4[lane + 64];
    float4 s0 = s4[lane], s1 = s4[lane + 64];
    float saa = dot4(a0, a0) + dot4(a1, a1);
    float sss = dot4(s0, s0) + dot4(s1, s1);
    float sas = dot4(a0, s0) + dot4(a1, s1);
    for (int m = 1; m < 64; m <<= 1) {
        saa += __shfl_xor(saa, m);
        sss += __shfl_xor(sss, m);
        sas += __shfl_xor(sas, m);
    }
    const float ra = rsqrtf(saa), rs = rsqrtf(sss);
    signed char* arow = aQ + (size_t)row * DIM;
    signed char* srow = sQ + (size_t)row * DIM;
    *(int*)(arow + lane * 4)       = q4(a0, ra * QS);
    *(int*)(arow + 256 + lane * 4) = q4(a1, ra * QS);
    *(int*)(srow + lane * 4)       = q4(s0, rs * QS);
    *(int*)(srow + 256 + lane * 4) = q4(s1, rs * QS);
    if (lane == 0) {
        diag[row] = sas * ra * rs * INV_T;
        // Uniform column weighting (incl. diagonal) is exact for the final
        // loss: only label==1 rows' lse is consumed, and those rows' diagonal
        // column has log_w==0 in the reference anyway. log2-weight: 0 or 1.
        lw2[row] = (labels[row] == 0) ? 1.0f : 0.0f;
        lsum[row] = 0.0f;
    }
}

// ---------------------------------------------------------------------------
// Repack row-major i8 [8192][512] -> fragment-major packed [8 kb][512 t16][1KB]
// Fragment (kb,t16) byte (grp,fr,b) = src[(t16*16+fr)*512 + kb*64 + grp*16+b],
// i.e. exactly the 16 B operand lane (fr,grp) feeds to mfma_i32_16x16x64_i8
// (the byte-identical pattern our r3-r8 LDS reads produced; absmax-0-proven).
// One block per (matrix, t16): 8 KB in via LDS bounce, 8 KB out coalesced.
// ---------------------------------------------------------------------------
__global__ __launch_bounds__(256) void repack_kernel(
    const signed char* __restrict__ qA, const signed char* __restrict__ qS,
    signed char* __restrict__ pA, signed char* __restrict__ pS) {
    __shared__ __align__(16) char sm[16 * 528];  // +16B row pad for banks
    const int bid = blockIdx.x;  // 1024 = 2 matrices x 512 t16
    const int mat = bid >> 9, t16 = bid & 511;
    const signed char* src = (mat ? qS : qA) + (size_t)t16 * 16 * 512;
    signed char* dst = mat ? pS : pA;
    const int tid = threadIdx.x;
#pragma unroll
    for (int r = 0; r < 2; ++r) {
        const int c = tid + r * 256;  // 512 chunks of 16 B
        const int row = c >> 5, off = (c & 31) * 16;
        *(i32x4*)&sm[row * 528 + off] = *(const i32x4*)&src[row * 512 + off];
    }
    __syncthreads();
#pragma unroll
    for (int r = 0; r < 2; ++r) {
        const int c = tid + r * 256;
        const int kb = c >> 6, lane = c & 63;
        const int grp = lane >> 4, fr = lane & 15;
        const i32x4 v = *(const i32x4*)&sm[fr * 528 + kb * 64 + grp * 16];
        *(i32x4*)&dst[(size_t)kb * 524288 + (size_t)t16 * 1024 + lane * 16] = v;
    }
}

// ---------------------------------------------------------------------------
// LDS-free streaming fused i8 GEMM + exp2 + row-sum (v9).
// Block = 4 waves = 64 rows x 256 cols; each wave owns a 64x64 tile.
// Every operand fetch = ONE coalesced 1 KB global_load_dwordx4 from the
// packed (fragment-major) arrays, L1/L2-resident. No LDS, no barriers, no
// staging: ping-pong named buffers (2-deep prologue, 1-deep steady prefetch);
// compiler's counted vmcnt scheduling orders load->MFMA. 2D XCD block map
// keeps per-XCD working set ~3 MB < 4 MB L2.
// ---------------------------------------------------------------------------
__global__ __launch_bounds__(256, 3) void lse_gemm(
    const signed char* __restrict__ pA, const signed char* __restrict__ pB,
    const float* __restrict__ lw2, float* __restrict__ lsum) {
    const int bid = blockIdx.x;  // 4096 = 8 xcd * 512
    const int xcd = bid & 7, idx = bid >> 3;
    const int rt = (xcd & 3) * 32 + (idx & 31);         // 0..127 (64-row tile)
    const int cg = (xcd >> 2) * 16 + (idx >> 5);        // 0..31 (256-col group)

    const int tid = threadIdx.x;
    const int wave = tid >> 6, lane = tid & 63;
    const int fr = lane & 15, grp = lane >> 4;

    const signed char* ap = pA + (size_t)(rt * 4) * 1024 + lane * 16;
    const signed char* bp = pB + (size_t)(cg * 16 + wave * 4) * 1024 + lane * 16;

    i32x4 acc[4][4] = {};
    i32x4 a0[4], b0[4], a1[4], b1[4];

#define LOADW(A, B, KB)                                                        \
    do {                                                                       \
        _Pragma("unroll")                                                      \
        for (int m = 0; m < 4; ++m)                                            \
            A[m] = *(const i32x4*)(ap + (size_t)(KB)*524288 + m * 1024);       \
        _Pragma("unroll")                                                      \
        for (int n = 0; n < 4; ++n)                                            \
            B[n] = *(const i32x4*)(bp + (size_t)(KB)*524288 + n * 1024);       \
    } while (0)

#define MFMA16(A, B)                                                           \
    do {                                                                       \
        _Pragma("unroll")                                                      \
        for (int m = 0; m < 4; ++m)                                            \
            _Pragma("unroll")                                                  \
            for (int n = 0; n < 4; ++n)                                        \
                acc[m][n] = __builtin_amdgcn_mfma_i32_16x16x64_i8(             \
                    A[m], B[n], acc[m][n], 0, 0, 0);                           \
    } while (0)

    LOADW(a0, b0, 0);
    LOADW(a1, b1, 1);
    MFMA16(a0, b0);
    LOADW(a0, b0, 2);
    MFMA16(a1, b1);
    LOADW(a1, b1, 3);
    MFMA16(a0, b0);
    LOADW(a0, b0, 4);
    MFMA16(a1, b1);
    LOADW(a1, b1, 5);
    MFMA16(a0, b0);
    LOADW(a0, b0, 6);
    MFMA16(a1, b1);
    LOADW(a1, b1, 7);
    MFMA16(a0, b0);
    MFMA16(a1, b1);
#undef LOADW
#undef MFMA16

    // Epilogue: uniform column weights, hw exp2, per-row reduce, atomicAdd.
    // C/D layout: col = lane&15, row = (lane>>4)*4 + j (verified r3-r8).
    const int row0 = rt * 64;
    const int col0 = cg * 256 + wave * 64;
    float lwv[4];
#pragma unroll
    for (int n = 0; n < 4; ++n)
        lwv[n] = lw2[col0 + n * 16 + fr];

    float rsum[4][4];
#pragma unroll
    for (int m = 0; m < 4; ++m)
#pragma unroll
        for (int j = 0; j < 4; ++j) {
            float s = 0.f;
#pragma unroll
            for (int n = 0; n < 4; ++n)
                s += hw_exp2(fmaf((float)acc[m][n][j], DEQ2, lwv[n]));
            rsum[m][j] = s;
        }

#pragma unroll
    for (int m = 0; m < 4; ++m)
#pragma unroll
        for (int j = 0; j < 4; ++j) {
            float v = rsum[m][j];
            v += __shfl_xor(v, 1);
            v += __shfl_xor(v, 2);
            v += __shfl_xor(v, 4);
            v += __shfl_xor(v, 8);
            if (fr == 0)
                atomicAdd(&lsum[row0 + m * 16 + grp * 4 + j], v);
        }
}

// 1024 threads, single block: final scalar reduction.
__global__ __launch_bounds__(1024) void finalize_kernel(
    const float* __restrict__ lsum, const float* __restrict__ diag,
    const int* __restrict__ labels, float* __restrict__ out) {
    const int tid = threadIdx.x;
    float sl = 0.f, sd = 0.f, mx = -1e9f;
    int np_ = 0, nn_ = 0;
#pragma unroll
    for (int i = tid; i < NROWS; i += 1024) {
        const float dg = diag[i];
        if (labels[i] == 1) {
            sl += logf(lsum[i]) - dg;
            sd += dg;
            np_++;
        } else {
            nn_++;
            mx = fmaxf(mx, dg);
        }
    }
    for (int m = 1; m < 64; m <<= 1) {
        sl += __shfl_xor(sl, m);
        sd += __shfl_xor(sd, m);
        mx = fmaxf(mx, __shfl_xor(mx, m));
        np_ += __shfl_xor(np_, m);
        nn_ += __shfl_xor(nn_, m);
    }
    __shared__ float rsl[16], rsd[16], rmx[16];
    __shared__ int rnp[16], rnn[16];
    const int wave = tid >> 6, lane = tid & 63;
    if (lane == 0) {
        rsl[wave] = sl; rsd[wave] = sd; rmx[wave] = mx;
        rnp[wave] = np_; rnn[wave] = nn_;
    }
    __syncthreads();
    if (tid == 0) {
        float SL = 0.f, SD = 0.f, MX = -1e9f;
        int NP = 0, NN = 0;
        for (int w = 0; w < 16; w++) {
            SL += rsl[w]; SD += rsd[w]; MX = fmaxf(MX, rmx[w]);
            NP += rnp[w]; NN += rnn[w];
        }
        const float infonce = SL / (float)NP;
        const float meanpos = SD / (float)NP;
        float pen = fmaxf(MX - meanpos + 0.2f, 0.0f);
        if (NN == 0) pen = 0.0f;
        out[0] = infonce + pen;
    }
}

extern "C" void kernel_launch(void* const* d_in, const int* in_sizes, int n_in,
                              void* d_out, int out_size, void* d_ws, size_t ws_size,
                              hipStream_t stream) {
    const float* A = (const float*)d_in[0];
    const float* S = (const float*)d_in[1];
    const int* labels = (const int*)d_in[2];
    float* out = (float*)d_out;

    char* ws = (char*)d_ws;
    signed char* aQ = (signed char*)ws;                               // 4 MB
    signed char* sQ = (signed char*)(ws + (size_t)NROWS * DIM);       // 4 MB
    signed char* pA = (signed char*)(ws + (size_t)NROWS * DIM * 2);   // 4 MB
    signed char* pB = (signed char*)(ws + (size_t)NROWS * DIM * 3);   // 4 MB
    char* p = ws + (size_t)NROWS * DIM * 4;
    float* diag = (float*)p;                // 32 KB
    float* lw2 = (float*)(p + 32768);       // 32 KB
    float* lsum = (float*)(p + 65536);      // 32 KB

    norm_kernel<<<NROWS / 4, 256, 0, stream>>>(A, S, labels, aQ, sQ, diag, lw2, lsum);
    repack_kernel<<<1024, 256, 0, stream>>>(aQ, sQ, pA, pB);
    lse_gemm<<<4096, 256, 0, stream>>>(pA, pB, lw2, lsum);
    finalize_kernel<<<1, 1024, 0, stream>>>(lsum, diag, labels, out);
}

// Round 10
// 65.769 us; speedup vs baseline: 1.2067x; 1.1014x over previous
//
#include <hip/hip_runtime.h>
#include <math.h>

#define NROWS 8192
#define DIM 512
#define INV_T 20.0f
#define QS 500.0f
// dequant * 1/T * log2(e), for exp2-based softmax accumulation
#define DEQ2 (INV_T * 1.4426950408889634f / (QS * QS))

typedef __attribute__((ext_vector_type(4))) int i32x4;

__device__ __forceinline__ void gload_lds16(const void* g, void* l) {
    __builtin_amdgcn_global_load_lds(
        (const __attribute__((address_space(1))) unsigned int*)g,
        (__attribute__((address_space(3))) unsigned int*)l, 16, 0, 0);
}

__device__ __forceinline__ float hw_exp2(float x) {
    float r;
    asm("v_exp_f32 %0, %1" : "=v"(r) : "v"(x));  // D = 2^S0, 1 inst
    return r;
}

__device__ __forceinline__ float dot4(float4 a, float4 b) {
    return a.x * b.x + a.y * b.y + a.z * b.z + a.w * b.w;
}

__device__ __forceinline__ int q4(float4 v, float s) {
    int b0 = __float2int_rn(fminf(fmaxf(v.x * s, -127.f), 127.f)) & 255;
    int b1 = __float2int_rn(fminf(fmaxf(v.y * s, -127.f), 127.f)) & 255;
    int b2 = __float2int_rn(fminf(fmaxf(v.z * s, -127.f), 127.f)) & 255;
    int b3 = __float2int_rn(fminf(fmaxf(v.w * s, -127.f), 127.f)) & 255;
    return b0 | (b1 << 8) | (b2 << 16) | (b3 << 24);
}

// One wave per row: L2-normalize, quantize to i8 (scale QS), exact fp32 diag,
// column log2-weights (0 or 1), zero row-sum accumulator.
__global__ __launch_bounds__(256) void norm_kernel(
    const float* __restrict__ A, const float* __restrict__ S,
    const int* __restrict__ labels, signed char* __restrict__ aQ,
    signed char* __restrict__ sQ, float* __restrict__ diag,
    float* __restrict__ lw2, float* __restrict__ lsum) {
    const int wave = threadIdx.x >> 6, lane = threadIdx.x & 63;
    const int row = blockIdx.x * 4 + wave;
    const float4* a4 = (const float4*)(A + (size_t)row * DIM);
    const float4* s4 = (const float4*)(S + (size_t)row * DIM);
    float4 a0 = a4[lane], a1 = a4[lane + 64];
    float4 s0 = s4[lane], s1 = s4[lane + 64];
    float saa = dot4(a0, a0) + dot4(a1, a1);
    float sss = dot4(s0, s0) + dot4(s1, s1);
    float sas = dot4(a0, s0) + dot4(a1, s1);
    for (int m = 1; m < 64; m <<= 1) {
        saa += __shfl_xor(saa, m);
        sss += __shfl_xor(sss, m);
        sas += __shfl_xor(sas, m);
    }
    const float ra = rsqrtf(saa), rs = rsqrtf(sss);
    signed char* arow = aQ + (size_t)row * DIM;
    signed char* srow = sQ + (size_t)row * DIM;
    *(int*)(arow + lane * 4)       = q4(a0, ra * QS);
    *(int*)(arow + 256 + lane * 4) = q4(a1, ra * QS);
    *(int*)(srow + lane * 4)       = q4(s0, rs * QS);
    *(int*)(srow + 256 + lane * 4) = q4(s1, rs * QS);
    if (lane == 0) {
        diag[row] = sas * ra * rs * INV_T;
        // Uniform column weighting (incl. diagonal) is exact for the final
        // loss: only label==1 rows' lse is consumed, and those rows' diagonal
        // column has log_w==0 in the reference anyway. log2-weight: 0 or 1.
        lw2[row] = (labels[row] == 0) ? 1.0f : 0.0f;
        lsum[row] = 0.0f;
    }
}

// ---------------------------------------------------------------------------
// 256x256-tile phased i8 GEMM + exp2 + row-sum (v10, m201-style adapted).
// 1024 threads = 16 waves (4x4), wave C = 64x64 (acc 64 VGPR). Block sweeps
// 4 column-tiles (cols ctg*1024..+1024) -> 32 K-steps. Per K-step: stage
// 32 KB (1 A + 1 B gload_lds per thread) into 64 KB LDS dbuf, counted
// vmcnt(2) (prev step's loads, ~1300 cyc lead -> wait~0), barrier, 8 ds_read
// b128 (base+immediate), lgkmcnt(0)+sched_barrier, setprio'd 16 MFMA,
// barrier. Per-ct epilogue is VALU-only. Grid 256 = 1 block/CU (4 waves/
// SIMD). Bijective 2D XCD map: per-XCD set = 1 MB A + 2 MB B < 4 MB L2.
// Swizzles: r3/r4-verified 4-slot involution (both sides).
// ---------------------------------------------------------------------------
__global__ __launch_bounds__(1024) void lse_gemm(
    const signed char* __restrict__ Aq, const signed char* __restrict__ Bq,
    const float* __restrict__ lw2, float* __restrict__ lsum) {
    __shared__ __align__(16) char lds[65536];
    // layout: buf0: A @0, B @16K; buf1: A @32K, B @48K

    const int bid = blockIdx.x;  // 256 blocks
    const int xcd = bid & 7, idx = bid >> 3;        // assume bid%8 -> XCD
    const int rt = (xcd >> 1) * 8 + (idx & 7);      // 0..31
    const int ctg = (xcd & 1) * 4 + (idx >> 3);     // 0..7
    const int row0 = rt * 256;
    const int colg = ctg * 1024;

    const int tid = threadIdx.x;
    const int wid = tid >> 6, lane = tid & 63;
    const int wr = wid >> 2, wc = wid & 3;          // 4x4 wave grid
    const int fr = lane & 15, grp = lane >> 4;

    // staging: thread t -> row t>>2 (0..255), phys slot t&3; fetch logical
    // slot (t&3)^((row>>1)&3) = (t&3)^((t>>3)&3)  [involution, verified]
    const int srow = tid >> 2;
    const int sl = (tid & 3) ^ ((tid >> 3) & 3);
    const signed char* aSrc = Aq + (size_t)(row0 + srow) * DIM + sl * 16;
    const signed char* bSrc = Bq + (size_t)(colg + srow) * DIM + sl * 16;
    char* dstA = lds + tid * 16;          // + buf*32768
    char* dstB = lds + 16384 + tid * 16;  // + buf*32768

    // K-step TT (0..31): ct = TT>>3, k = TT&7.
    // B tile rows for ct: colg + ct*256 + srow -> bSrc + ct*(256*512)
#define STAGE(buf, TT)                                                        \
    do {                                                                      \
        const int ct_ = (TT) >> 3, k_ = (TT) & 7;                             \
        gload_lds16(aSrc + k_ * 64, dstA + (buf) * 32768);                    \
        gload_lds16(bSrc + ct_ * 131072 + k_ * 64, dstB + (buf) * 32768);     \
    } while (0)

    // fragment reads: row R = (wr|wc)*64 + m*16 + fr, byte R*64 + pslot*16,
    // pslot = grp ^ ((R>>1)&3) = grp ^ ((fr>>1)&3) (R-fr part is mult of 16)
    const int ps = (grp ^ ((fr >> 1) & 3)) << 4;
    const char* rdA = lds + (wr * 64 + fr) * 64 + ps;
    const char* rdB = lds + 16384 + (wc * 64 + fr) * 64 + ps;

    STAGE(0, 0);

    i32x4 acc[4][4] = {};
#pragma unroll 2
    for (int T = 0; T < 32; ++T) {
        const int buf = T & 1;
        if (T < 31) {
            STAGE(buf ^ 1, T + 1);
            asm volatile("s_waitcnt vmcnt(2)" ::: "memory");
        } else {
            asm volatile("s_waitcnt vmcnt(0)" ::: "memory");
        }
        __builtin_amdgcn_s_barrier();  // buf(T) staged by all waves

        i32x4 a[4], b[4];
#pragma unroll
        for (int m = 0; m < 4; ++m)
            a[m] = *(const i32x4*)(rdA + buf * 32768 + m * 1024);
#pragma unroll
        for (int n = 0; n < 4; ++n)
            b[n] = *(const i32x4*)(rdB + buf * 32768 + n * 1024);
        asm volatile("s_waitcnt lgkmcnt(0)" ::: "memory");
        __builtin_amdgcn_sched_barrier(0);  // rule 18: pin MFMA after lgkm

        __builtin_amdgcn_s_setprio(1);
#pragma unroll
        for (int m = 0; m < 4; ++m)
#pragma unroll
            for (int n = 0; n < 4; ++n)
                acc[m][n] = __builtin_amdgcn_mfma_i32_16x16x64_i8(
                    a[m], b[n], acc[m][n], 0, 0, 0);
        __builtin_amdgcn_s_setprio(0);

        if ((T & 7) == 7) {
            // per-ct epilogue (VALU only): dequant -> exp2 -> reduce -> atomic
            const int ct = T >> 3;
            const int col0 = colg + ct * 256 + wc * 64;
            float lwv[4];
#pragma unroll
            for (int n = 0; n < 4; ++n)
                lwv[n] = lw2[col0 + n * 16 + fr];
#pragma unroll
            for (int m = 0; m < 4; ++m)
#pragma unroll
                for (int j = 0; j < 4; ++j) {
                    float s = 0.f;
#pragma unroll
                    for (int n = 0; n < 4; ++n)
                        s += hw_exp2(fmaf((float)acc[m][n][j], DEQ2, lwv[n]));
                    s += __shfl_xor(s, 1);
                    s += __shfl_xor(s, 2);
                    s += __shfl_xor(s, 4);
                    s += __shfl_xor(s, 8);
                    if (fr == 0)
                        atomicAdd(&lsum[row0 + wr * 64 + m * 16 + grp * 4 + j], s);
                }
#pragma unroll
            for (int m = 0; m < 4; ++m)
#pragma unroll
                for (int n = 0; n < 4; ++n)
                    acc[m][n] = i32x4{0, 0, 0, 0};
        }
        __builtin_amdgcn_s_barrier();  // buf(T) reads done before overwrite
    }
#undef STAGE
}

// 1024 threads, single block: final scalar reduction.
__global__ __launch_bounds__(1024) void finalize_kernel(
    const float* __restrict__ lsum, const float* __restrict__ diag,
    const int* __restrict__ labels, float* __restrict__ out) {
    const int tid = threadIdx.x;
    float sl = 0.f, sd = 0.f, mx = -1e9f;
    int np_ = 0, nn_ = 0;
#pragma unroll
    for (int i = tid; i < NROWS; i += 1024) {
        const float dg = diag[i];
        if (labels[i] == 1) {
            sl += logf(lsum[i]) - dg;
            sd += dg;
            np_++;
        } else {
            nn_++;
            mx = fmaxf(mx, dg);
        }
    }
    for (int m = 1; m < 64; m <<= 1) {
        sl += __shfl_xor(sl, m);
        sd += __shfl_xor(sd, m);
        mx = fmaxf(mx, __shfl_xor(mx, m));
        np_ += __shfl_xor(np_, m);
        nn_ += __shfl_xor(nn_, m);
    }
    __shared__ float rsl[16], rsd[16], rmx[16];
    __shared__ int rnp[16], rnn[16];
    const int wave = tid >> 6, lane = tid & 63;
    if (lane == 0) {
        rsl[wave] = sl; rsd[wave] = sd; rmx[wave] = mx;
        rnp[wave] = np_; rnn[wave] = nn_;
    }
    __syncthreads();
    if (tid == 0) {
        float SL = 0.f, SD = 0.f, MX = -1e9f;
        int NP = 0, NN = 0;
        for (int w = 0; w < 16; w++) {
            SL += rsl[w]; SD += rsd[w]; MX = fmaxf(MX, rmx[w]);
            NP += rnp[w]; NN += rnn[w];
        }
        const float infonce = SL / (float)NP;
        const float meanpos = SD / (float)NP;
        float pen = fmaxf(MX - meanpos + 0.2f, 0.0f);
        if (NN == 0) pen = 0.0f;
        out[0] = infonce + pen;
    }
}

extern "C" void kernel_launch(void* const* d_in, const int* in_sizes, int n_in,
                              void* d_out, int out_size, void* d_ws, size_t ws_size,
                              hipStream_t stream) {
    const float* A = (const float*)d_in[0];
    const float* S = (const float*)d_in[1];
    const int* labels = (const int*)d_in[2];
    float* out = (float*)d_out;

    char* ws = (char*)d_ws;
    signed char* aQ = (signed char*)ws;                          // 4 MB
    signed char* sQ = (signed char*)(ws + (size_t)NROWS * DIM);  // 4 MB
    char* p = ws + (size_t)NROWS * DIM * 2;
    float* diag = (float*)p;                // 32 KB
    float* lw2 = (float*)(p + 32768);       // 32 KB
    float* lsum = (float*)(p + 65536);      // 32 KB

    norm_kernel<<<NROWS / 4, 256, 0, stream>>>(A, S, labels, aQ, sQ, diag, lw2, lsum);
    lse_gemm<<<256, 1024, 0, stream>>>(aQ, sQ, lw2, lsum);
    finalize_kernel<<<1, 1024, 0, stream>>>(lsum, diag, labels, out);
}